// Round 11
// baseline (448.915 us; speedup 1.0000x reference)
//
#include <hip/hip_runtime.h>

#define SUPPORT 512
#define TARGET  65024
#define NCLS    64
#define NQUAD   (TARGET / 4)       // 16256 row-quads for direct part
#define GS_ROWS 64
#define GS_BLK  (TARGET / GS_ROWS) // 1016 stream blocks
#define PH_BLK  2032               // pos_hist blocks (8 threads/row, 32 rows/block)
#define DR_BLK  1024               // direct blocks
#define PHGRID  (PH_BLK + DR_BLK)

struct Accum {
    // ---- zeroed by prep ----
    float hist_fr_sp[8][80];    // spread Σfrac per bin (pos elements)
    float hist_cnt_sp[8][80];   // spread counts per bin (pos elements)
    float sum_all[8];
    float nll_sum[8];
    unsigned done_ph;
    unsigned done_gs;
    // ---- fully overwritten, no zeroing needed ----
    float A[80];                // C[idx+1]
    float B[80];                // Hpos[idx+1]
    float spos;                 // closed-form sum_pos
    float pos_num;              // total positive count
    int   cls_off[NCLS + 1];
    int   cls_col[SUPPORT];
};
#define ZERO_WORDS (8 * 80 * 2 + 8 + 8 + 2)   // 1298 words

__device__ __forceinline__ void lds_fadd(float* p, float v) {
    __hip_atomic_fetch_add(p, v, __ATOMIC_RELAXED, __HIP_MEMORY_SCOPE_WORKGROUP);
}
__device__ __forceinline__ float agent_loadf(const float* p) {
    return __hip_atomic_load(p, __ATOMIC_RELAXED, __HIP_MEMORY_SCOPE_AGENT);
}

// ---------------------------------------------------------------- prep (zero + CSR)
__global__ void prep_kernel(const int* __restrict__ labels, Accum* ws) {
    __shared__ int sh_cnt[NCLS], sh_off[NCLS], cur[NCLS];
    const int t = threadIdx.x;                 // 512 threads
    int* wsi = (int*)ws;
    for (int i = t; i < ZERO_WORDS; i += 512) wsi[i] = 0;
    if (t < NCLS) { sh_cnt[t] = 0; cur[t] = 0; }
    __syncthreads();
    const int c = labels[t];
    atomicAdd(&sh_cnt[c], 1);
    __syncthreads();
    if (t == 0) {
        int o = 0;
        for (int i = 0; i < NCLS; ++i) { sh_off[i] = o; ws->cls_off[i] = o; o += sh_cnt[i]; }
        ws->cls_off[NCLS] = o;
    }
    __syncthreads();
    const int slot = atomicAdd(&cur[c], 1);
    ws->cls_col[sh_off[c] + slot] = t;
}

// ---------------------------------------------------------------- pos_hist + direct + cdf tail
__global__ __launch_bounds__(256) void phdir_kernel(const float* __restrict__ ip,
                                                    const float* __restrict__ logits,
                                                    const int* __restrict__ labels,
                                                    Accum* __restrict__ ws) {
    __shared__ float redv[4];
    __shared__ unsigned ticket_s;
    const int tid = threadIdx.x;
    if (blockIdx.x < PH_BLK) {
        // ---- pos (Sfr, Cnt) histogram: 8 threads per target row, 32 rows/block
        __shared__ float hfr[76][8];
        __shared__ float hcnt[76][8];
        __shared__ int   colL[SUPPORT];
        __shared__ int   offL[NCLS + 1];
        for (int i = tid; i < 76 * 8; i += 256) {
            (&hfr[0][0])[i] = 0.0f;
            (&hcnt[0][0])[i] = 0.0f;
        }
        for (int i = tid; i < SUPPORT; i += 256) colL[i] = ws->cls_col[i];
        if (tid <= NCLS) offL[tid] = ws->cls_off[tid];
        __syncthreads();

        const int row = (blockIdx.x * 256 + tid) >> 3;
        const int sl  = tid & 7;
        {
            const int c    = labels[SUPPORT + row];
            const int base = offL[c];
            const int cnt  = offL[c + 1] - base;
            const float* rptr = ip + (size_t)row * SUPPORT;
            for (int j = sl; j < cnt; j += 8) {
                const float s  = rptr[colL[base + j]];
                const float u  = s * 75.0f;
                const float fl = floorf(u);
                const int idx  = (int)fl;            // 0..74 guaranteed (s in [0,1))
                lds_fadd(&hfr[idx][sl],  u - fl);
                lds_fadd(&hcnt[idx][sl], 1.0f);
            }
        }
        __syncthreads();
        if (tid < 76) {
            float a = 0.0f, b = 0.0f;
            #pragma unroll
            for (int r = 0; r < 8; ++r) { a += hfr[tid][r]; b += hcnt[tid][r]; }
            if (a != 0.0f) unsafeAtomicAdd(&ws->hist_fr_sp[blockIdx.x & 7][tid], a);
            if (b != 0.0f) unsafeAtomicAdd(&ws->hist_cnt_sp[blockIdx.x & 7][tid], b);
        }
    } else {
        // ---- direct loss: 4 rows per wave, 16-lane group per row
        const int bid  = blockIdx.x - PH_BLK;
        const int wid  = tid >> 6;
        const int lane = tid & 63;
        const int sub  = lane >> 4;
        const int grpb = lane & ~15;

        float lsum = 0.0f;
        for (int q = bid * 4 + wid; q < NQUAD; q += DR_BLK * 4) {
            const float4 x = reinterpret_cast<const float4*>(logits)[q * 64 + lane];
            const int lab  = labels[SUPPORT + q * 4 + sub];
            float m = fmaxf(fmaxf(x.x, x.y), fmaxf(x.z, x.w));
            #pragma unroll
            for (int off = 1; off < 16; off <<= 1) m = fmaxf(m, __shfl_xor(m, off));
            float e = __expf(x.x - m) + __expf(x.y - m) + __expf(x.z - m) + __expf(x.w - m);
            #pragma unroll
            for (int off = 1; off < 16; off <<= 1) e += __shfl_xor(e, off);
            const int l3 = lab & 3;
            const float sel = l3 == 0 ? x.x : l3 == 1 ? x.y : l3 == 2 ? x.z : x.w;
            const float xl = __shfl(sel, grpb + (lab >> 2));
            if ((lane & 15) == 0) lsum += m + __logf(e) - xl;
        }
        #pragma unroll
        for (int off = 1; off < 64; off <<= 1) lsum += __shfl_xor(lsum, off);
        if (lane == 0) redv[wid] = lsum;
        __syncthreads();
        if (tid == 0)
            unsafeAtomicAdd(&ws->nll_sum[bid & 7], redv[0] + redv[1] + redv[2] + redv[3]);
    }

    // ---- last-block tail: reduce hist, build tables, closed-form spos + pos_num
    __threadfence();
    __syncthreads();
    if (tid == 0)
        ticket_s = __hip_atomic_fetch_add(&ws->done_ph, 1u, __ATOMIC_ACQ_REL,
                                          __HIP_MEMORY_SCOPE_AGENT);
    __syncthreads();
    if (ticket_s == PHGRID - 1) {
        __shared__ float Sfr[80], Cnt[80];
        if (tid < 76) {
            float a = 0.0f, b = 0.0f;
            #pragma unroll
            for (int r = 0; r < 8; ++r) {
                a += agent_loadf(&ws->hist_fr_sp[r][tid]);
                b += agent_loadf(&ws->hist_cnt_sp[r][tid]);
            }
            Sfr[tid] = a; Cnt[tid] = b;
        }
        if (tid >= 76 && tid < 80) { Sfr[tid] = 0.0f; Cnt[tid] = 0.0f; }
        __syncthreads();
        if (tid == 0) {
            float prevS = 0.0f, prevN = 0.0f, cacc = 0.0f;
            double sp = 0.0, pn = 0.0;
            for (int i = 0; i <= 76; ++i) {
                const float Si = (i < 76) ? Sfr[i] : 0.0f;
                const float Ni = (i < 76) ? Cnt[i] : 0.0f;
                const float Hi = Si + prevN - prevS;     // pos soft-hist H[i]
                cacc += Hi;                              // C[i]
                if (i >= 1) {
                    ws->A[i - 1] = cacc;                 // A[k]=C[k+1]
                    ws->B[i - 1] = Hi;                   // B[k]=H[k+1]
                    sp += (double)prevN * cacc - (double)prevS * Hi;
                }
                pn += (double)Ni;
                prevS = Si; prevN = Ni;
            }
            for (int i = 76; i < 80; ++i) { ws->A[i] = 0.0f; ws->B[i] = 0.0f; }
            ws->spos = (float)sp;
            ws->pos_num = (float)pn;
        }
    }
}

// ---------------------------------------------------------------- main pass + final tail
// Pure stream: block owns 64 contiguous rows (32 steps x 256 float4).
// Named-register 8-deep load pipeline; per element ~9 VALU + 1 staggered
// ds_read_b64. Last block computes the outputs.
__global__ __launch_bounds__(256, 4) void gather_kernel(const float* __restrict__ ip,
                                                        Accum* __restrict__ ws,
                                                        float* __restrict__ out) {
    __shared__ float2 tab[76 * 16];   // 16-way replicated, idx-staggered
    __shared__ float red[4];
    __shared__ unsigned ticket_s;
    const int tid = threadIdx.x;
    const int c16 = tid & 15;

    for (int i = tid; i < 76 * 16; i += 256) {
        const int idx = i >> 4, cc = i & 15;
        tab[(idx << 4) + ((cc + idx) & 15)] = make_float2(ws->A[idx], ws->B[idx]);
    }
    __syncthreads();

    const float4* base = reinterpret_cast<const float4*>(ip)
                       + (size_t)blockIdx.x * (GS_ROWS * 128) + tid;

    float s0 = 0.0f, s1 = 0.0f;
    float4 qa0, qa1, qa2, qa3, qa4, qa5, qa6, qa7;
    float4 qb0, qb1, qb2, qb3, qb4, qb5, qb6, qb7;

#define LDA(T) { qa0 = base[((T)+0)*256]; qa1 = base[((T)+1)*256]; \
                 qa2 = base[((T)+2)*256]; qa3 = base[((T)+3)*256]; \
                 qa4 = base[((T)+4)*256]; qa5 = base[((T)+5)*256]; \
                 qa6 = base[((T)+6)*256]; qa7 = base[((T)+7)*256]; }
#define LDB(T) { qb0 = base[((T)+0)*256]; qb1 = base[((T)+1)*256]; \
                 qb2 = base[((T)+2)*256]; qb3 = base[((T)+3)*256]; \
                 qb4 = base[((T)+4)*256]; qb5 = base[((T)+5)*256]; \
                 qb6 = base[((T)+6)*256]; qb7 = base[((T)+7)*256]; }
#define PE(S, ACC) { const float u = (S) * 75.0f; const float fl = floorf(u);     \
                     const float fr = u - fl; const int idx = (int)fl;            \
                     const float2 ab = tab[(idx << 4) + ((c16 + idx) & 15)];      \
                     ACC += fmaf(-fr, ab.y, ab.x); }
#define P1(Q) { PE(Q.x, s0) PE(Q.y, s1) PE(Q.z, s0) PE(Q.w, s1) }
#define PA()  { P1(qa0) P1(qa1) P1(qa2) P1(qa3) P1(qa4) P1(qa5) P1(qa6) P1(qa7) }
#define PB()  { P1(qb0) P1(qb1) P1(qb2) P1(qb3) P1(qb4) P1(qb5) P1(qb6) P1(qb7) }

    LDA(0);
    LDB(8);
    PA();  LDA(16);
    PB();  LDB(24);
    PA();
    PB();

#undef LDA
#undef LDB
#undef PE
#undef P1
#undef PA
#undef PB

    float s_all = s0 + s1;
    #pragma unroll
    for (int off = 1; off < 64; off <<= 1) s_all += __shfl_xor(s_all, off);
    if ((tid & 63) == 0) red[tid >> 6] = s_all;
    __syncthreads();
    if (tid == 0)
        unsafeAtomicAdd(&ws->sum_all[blockIdx.x & 7], red[0] + red[1] + red[2] + red[3]);

    // ---- last-block tail: finalize outputs
    __threadfence();
    __syncthreads();
    if (tid == 0) {
        ticket_s = __hip_atomic_fetch_add(&ws->done_gs, 1u, __ATOMIC_ACQ_REL,
                                          __HIP_MEMORY_SCOPE_AGENT);
    }
    __syncthreads();
    if (ticket_s == GS_BLK - 1 && tid == 0) {
        double S = 0.0, nll = 0.0;
        for (int i = 0; i < 8; ++i) {
            S   += (double)agent_loadf(&ws->sum_all[i]);
            nll += (double)agent_loadf(&ws->nll_sum[i]);
        }
        const double pos = (double)agent_loadf(&ws->pos_num);
        const double tot = (double)TARGET * (double)SUPPORT;
        out[0] = (float)((S - (double)agent_loadf(&ws->spos)) / (pos * (tot - pos)));
        out[1] = (float)(nll / (double)TARGET);
    }
}

// ---------------------------------------------------------------- launch
extern "C" void kernel_launch(void* const* d_in, const int* in_sizes, int n_in,
                              void* d_out, int out_size, void* d_ws, size_t ws_size,
                              hipStream_t stream) {
    const float* logits = (const float*)d_in[0];   // (65024, 64) f32
    const float* ip     = (const float*)d_in[1];   // (65024, 512) f32
    const int*   labels = (const int*)d_in[2];     // (65536,) int
    float* out = (float*)d_out;
    Accum* ws  = (Accum*)d_ws;

    prep_kernel<<<1, 512, 0, stream>>>(labels, ws);
    phdir_kernel<<<PHGRID, 256, 0, stream>>>(ip, logits, labels, ws);
    gather_kernel<<<GS_BLK, 256, 0, stream>>>(ip, ws, out);
}

// Round 12
// 76.787 us; speedup vs baseline: 5.8463x; 5.8463x over previous
//
#include <hip/hip_runtime.h>

#define SUPPORT 512
#define TARGET  65024
#define NCLS    64
#define NQUAD   (TARGET / 4)       // 16256 row-quads for direct part
#define GS_ROWS 64
#define GS_BLK  (TARGET / GS_ROWS) // 1016 stream blocks
#define PH_BLK  2032               // pos_hist blocks (8 threads/row, 32 rows/block)
#define DR_BLK  1024               // direct blocks (appended to stream dispatch)

struct Accum {
    // ---- zeroed by prep ----
    float hist_fr_sp[8][80];    // spread Σfrac per bin (pos elements)
    float hist_cnt_sp[8][80];   // spread counts per bin (pos elements)
    float sum_all[8];
    float nll_sum[8];
    // ---- fully overwritten, no zeroing needed ----
    float Ta[80];               // C[k+1] + k*H[k+1]
    float Tb[80];               // H[k+1]
    float spos;                 // closed-form sum_pos
    float pos_num;              // total positive count
    int   cls_off[NCLS + 1];
    int   cls_col[SUPPORT];
};
#define ZERO_WORDS (8 * 80 * 2 + 8 + 8)   // 1296 words

__device__ __forceinline__ void lds_fadd(float* p, float v) {
    __hip_atomic_fetch_add(p, v, __ATOMIC_RELAXED, __HIP_MEMORY_SCOPE_WORKGROUP);
}

// ---------------------------------------------------------------- prep (zero + CSR)
__global__ void prep_kernel(const int* __restrict__ labels, Accum* ws) {
    __shared__ int sh_cnt[NCLS], sh_off[NCLS], cur[NCLS];
    const int t = threadIdx.x;                 // 512 threads
    int* wsi = (int*)ws;
    for (int i = t; i < ZERO_WORDS; i += 512) wsi[i] = 0;
    if (t < NCLS) { sh_cnt[t] = 0; cur[t] = 0; }
    __syncthreads();
    const int c = labels[t];
    atomicAdd(&sh_cnt[c], 1);
    __syncthreads();
    if (t == 0) {
        int o = 0;
        for (int i = 0; i < NCLS; ++i) { sh_off[i] = o; ws->cls_off[i] = o; o += sh_cnt[i]; }
        ws->cls_off[NCLS] = o;
    }
    __syncthreads();
    const int slot = atomicAdd(&cur[c], 1);
    ws->cls_col[sh_off[c] + slot] = t;
}

// ---------------------------------------------------------------- pos (Sfr,Cnt) histogram
// 8 threads per target row gather the positive columns (~8/row avg).
__global__ __launch_bounds__(256) void poshist_kernel(const float* __restrict__ ip,
                                                      const int* __restrict__ labels,
                                                      Accum* __restrict__ ws) {
    __shared__ float hfr[76][8];
    __shared__ float hcnt[76][8];
    __shared__ int   colL[SUPPORT];
    __shared__ int   offL[NCLS + 1];
    const int tid = threadIdx.x;
    for (int i = tid; i < 76 * 8; i += 256) {
        (&hfr[0][0])[i] = 0.0f;
        (&hcnt[0][0])[i] = 0.0f;
    }
    for (int i = tid; i < SUPPORT; i += 256) colL[i] = ws->cls_col[i];
    if (tid <= NCLS) offL[tid] = ws->cls_off[tid];
    __syncthreads();

    const int row = (blockIdx.x * 256 + tid) >> 3;
    const int sl  = tid & 7;
    {
        const int c    = labels[SUPPORT + row];
        const int base = offL[c];
        const int cnt  = offL[c + 1] - base;
        const float* rptr = ip + (size_t)row * SUPPORT;
        for (int j = sl; j < cnt; j += 8) {
            const float s  = rptr[colL[base + j]];
            const float u  = s * 75.0f;
            const float fl = floorf(u);
            const int idx  = (int)fl;            // 0..74 guaranteed (s in [0,1))
            lds_fadd(&hfr[idx][sl],  u - fl);
            lds_fadd(&hcnt[idx][sl], 1.0f);
        }
    }
    __syncthreads();
    if (tid < 76) {
        float a = 0.0f, b = 0.0f;
        #pragma unroll
        for (int r = 0; r < 8; ++r) { a += hfr[tid][r]; b += hcnt[tid][r]; }
        if (a != 0.0f) unsafeAtomicAdd(&ws->hist_fr_sp[blockIdx.x & 7][tid], a);
        if (b != 0.0f) unsafeAtomicAdd(&ws->hist_cnt_sp[blockIdx.x & 7][tid], b);
    }
}

// ---------------------------------------------------------------- cdf: fused tables + closed-form spos/pos_num
__global__ void cdf_kernel(Accum* ws) {
    __shared__ float Sfr[80], Cnt[80];
    const int t = threadIdx.x;
    if (t < 76) {
        float a = 0.0f, b = 0.0f;
        #pragma unroll
        for (int r = 0; r < 8; ++r) { a += ws->hist_fr_sp[r][t]; b += ws->hist_cnt_sp[r][t]; }
        Sfr[t] = a; Cnt[t] = b;
    }
    if (t >= 76 && t < 80) { Sfr[t] = 0.0f; Cnt[t] = 0.0f; }
    __syncthreads();
    if (t == 0) {
        float prevS = 0.0f, prevN = 0.0f, cacc = 0.0f;
        double sp = 0.0, pn = 0.0;
        for (int i = 0; i <= 76; ++i) {
            const float Si = (i < 76) ? Sfr[i] : 0.0f;
            const float Ni = (i < 76) ? Cnt[i] : 0.0f;
            const float Hi = Si + prevN - prevS;     // pos soft-hist H[i]
            cacc += Hi;                              // C[i]
            if (i >= 1) {
                const int k = i - 1;
                ws->Ta[k] = cacc + (float)k * Hi;    // C[k+1] + k*H[k+1]
                ws->Tb[k] = Hi;                      // H[k+1]
                sp += (double)prevN * cacc - (double)prevS * Hi;
            }
            pn += (double)Ni;
            prevS = Si; prevN = Ni;
        }
        for (int i = 77; i < 80; ++i) { ws->Ta[i] = 0.0f; ws->Tb[i] = 0.0f; }
        ws->spos = (float)sp;
        ws->pos_num = (float)pn;
    }
}

// ---------------------------------------------------------------- stream + direct (one dispatch)
// Blocks [0,GS_BLK): pure stream, 64 rows each, named-register 8-deep pipeline.
// Per element: u=s*75; idx=(int)u; b64 table read; sa+=Ta; sb=fma(u,Tb,sb).
// Blocks [GS_BLK, GS_BLK+DR_BLK): direct loss, 4 rows/wave.
__global__ __launch_bounds__(256, 4) void stream_kernel(const float* __restrict__ ip,
                                                        const float* __restrict__ logits,
                                                        const int* __restrict__ labels,
                                                        Accum* __restrict__ ws) {
    __shared__ float2 tab[76 * 16];   // 16-way replicated fused table
    __shared__ float red[8];
    const int tid = threadIdx.x;

    if (blockIdx.x >= GS_BLK) {
        // ---- direct loss: 4 rows per wave, 16-lane group per row
        const int bid  = blockIdx.x - GS_BLK;
        const int wid  = tid >> 6;
        const int lane = tid & 63;
        const int sub  = lane >> 4;
        const int grpb = lane & ~15;

        float lsum = 0.0f;
        for (int q = bid * 4 + wid; q < NQUAD; q += DR_BLK * 4) {
            const float4 x = reinterpret_cast<const float4*>(logits)[q * 64 + lane];
            const int lab  = labels[SUPPORT + q * 4 + sub];
            float m = fmaxf(fmaxf(x.x, x.y), fmaxf(x.z, x.w));
            #pragma unroll
            for (int off = 1; off < 16; off <<= 1) m = fmaxf(m, __shfl_xor(m, off));
            float e = __expf(x.x - m) + __expf(x.y - m) + __expf(x.z - m) + __expf(x.w - m);
            #pragma unroll
            for (int off = 1; off < 16; off <<= 1) e += __shfl_xor(e, off);
            const int l3 = lab & 3;
            const float sel = l3 == 0 ? x.x : l3 == 1 ? x.y : l3 == 2 ? x.z : x.w;
            const float xl = __shfl(sel, grpb + (lab >> 2));
            if ((lane & 15) == 0) lsum += m + __logf(e) - xl;
        }
        #pragma unroll
        for (int off = 1; off < 64; off <<= 1) lsum += __shfl_xor(lsum, off);
        if (lane == 0) red[wid] = lsum;
        __syncthreads();
        if (tid == 0)
            unsafeAtomicAdd(&ws->nll_sum[bid & 7], red[0] + red[1] + red[2] + red[3]);
        return;
    }

    // ---- stream path
    const int c16 = tid & 15;
    for (int i = tid; i < 76 * 16; i += 256)
        tab[i] = make_float2(ws->Ta[i >> 4], ws->Tb[i >> 4]);
    __syncthreads();

    const float4* base = reinterpret_cast<const float4*>(ip)
                       + (size_t)blockIdx.x * (GS_ROWS * 128) + tid;

    float sa0 = 0.0f, sb0 = 0.0f, sa1 = 0.0f, sb1 = 0.0f;
    float4 qa0, qa1, qa2, qa3, qa4, qa5, qa6, qa7;
    float4 qb0, qb1, qb2, qb3, qb4, qb5, qb6, qb7;

#define LDA(T) { qa0 = base[((T)+0)*256]; qa1 = base[((T)+1)*256]; \
                 qa2 = base[((T)+2)*256]; qa3 = base[((T)+3)*256]; \
                 qa4 = base[((T)+4)*256]; qa5 = base[((T)+5)*256]; \
                 qa6 = base[((T)+6)*256]; qa7 = base[((T)+7)*256]; }
#define LDB(T) { qb0 = base[((T)+0)*256]; qb1 = base[((T)+1)*256]; \
                 qb2 = base[((T)+2)*256]; qb3 = base[((T)+3)*256]; \
                 qb4 = base[((T)+4)*256]; qb5 = base[((T)+5)*256]; \
                 qb6 = base[((T)+6)*256]; qb7 = base[((T)+7)*256]; }
#define PE(S, SA, SB) { const float u = (S) * 75.0f; const int idx = (int)u;   \
                        const float2 ab = tab[(idx << 4) + c16];               \
                        SA += ab.x; SB = fmaf(u, ab.y, SB); }
#define P1(Q) { PE(Q.x, sa0, sb0) PE(Q.y, sa1, sb1) PE(Q.z, sa0, sb0) PE(Q.w, sa1, sb1) }
#define PA()  { P1(qa0) P1(qa1) P1(qa2) P1(qa3) P1(qa4) P1(qa5) P1(qa6) P1(qa7) }
#define PB()  { P1(qb0) P1(qb1) P1(qb2) P1(qb3) P1(qb4) P1(qb5) P1(qb6) P1(qb7) }

    LDA(0);
    LDB(8);
    PA();  LDA(16);
    PB();  LDB(24);
    PA();
    PB();

#undef LDA
#undef LDB
#undef PE
#undef P1
#undef PA
#undef PB

    float s_all = (sa0 + sa1) - (sb0 + sb1);
    #pragma unroll
    for (int off = 1; off < 64; off <<= 1) s_all += __shfl_xor(s_all, off);
    if ((tid & 63) == 0) red[tid >> 6] = s_all;
    __syncthreads();
    if (tid == 0)
        unsafeAtomicAdd(&ws->sum_all[blockIdx.x & 7], red[0] + red[1] + red[2] + red[3]);
}

// ---------------------------------------------------------------- finalize
__global__ void final_kernel(const Accum* __restrict__ ws, float* __restrict__ out) {
    if (threadIdx.x == 0 && blockIdx.x == 0) {
        double S = 0.0, nll = 0.0;
        for (int i = 0; i < 8; ++i) {
            S   += (double)ws->sum_all[i];
            nll += (double)ws->nll_sum[i];
        }
        const double pos = (double)ws->pos_num;
        const double tot = (double)TARGET * (double)SUPPORT;
        out[0] = (float)((S - (double)ws->spos) / (pos * (tot - pos)));
        out[1] = (float)(nll / (double)TARGET);
    }
}

// ---------------------------------------------------------------- launch
extern "C" void kernel_launch(void* const* d_in, const int* in_sizes, int n_in,
                              void* d_out, int out_size, void* d_ws, size_t ws_size,
                              hipStream_t stream) {
    const float* logits = (const float*)d_in[0];   // (65024, 64) f32
    const float* ip     = (const float*)d_in[1];   // (65024, 512) f32
    const int*   labels = (const int*)d_in[2];     // (65536,) int
    float* out = (float*)d_out;
    Accum* ws  = (Accum*)d_ws;

    prep_kernel<<<1, 512, 0, stream>>>(labels, ws);
    poshist_kernel<<<PH_BLK, 256, 0, stream>>>(ip, labels, ws);
    cdf_kernel<<<1, 128, 0, stream>>>(ws);
    stream_kernel<<<GS_BLK + DR_BLK, 256, 0, stream>>>(ip, logits, labels, ws);
    final_kernel<<<1, 64, 0, stream>>>(ws, out);
}

// Round 13
// 73.867 us; speedup vs baseline: 6.0773x; 1.0395x over previous
//
#include <hip/hip_runtime.h>

#define SUPPORT 512
#define TARGET  65024
#define NCLS    64
#define NQUAD   (TARGET / 4)       // 16256 row-quads for direct part
#define GS_ROWS 64
#define GS_BLK  (TARGET / GS_ROWS) // 1016 stream blocks
#define PH_BLK  2032               // pos_hist blocks (8 threads/row, 32 rows/block)
#define DR_BLK  1024               // direct blocks (in poshist dispatch)

struct Accum {
    // ---- zeroed by prep ----
    float hist_fr_sp[8][80];    // spread Σfrac per bin (pos elements)
    float hist_cnt_sp[8][80];   // spread counts per bin (pos elements)
    float sum_all[8];
    float nll_sum[8];
    // ---- written by stream block 0 / prep ----
    float spos;                 // closed-form sum_pos
    float pos_num;              // total positive count
    int   cls_off[NCLS + 1];
    int   cls_col[SUPPORT];
};
#define ZERO_WORDS (8 * 80 * 2 + 8 + 8)   // 1296 words

__device__ __forceinline__ void lds_fadd(float* p, float v) {
    __hip_atomic_fetch_add(p, v, __ATOMIC_RELAXED, __HIP_MEMORY_SCOPE_WORKGROUP);
}

// ---------------------------------------------------------------- prep (zero + CSR)
__global__ void prep_kernel(const int* __restrict__ labels, Accum* ws) {
    __shared__ int sh_cnt[NCLS], sh_off[NCLS], cur[NCLS];
    const int t = threadIdx.x;                 // 512 threads
    int* wsi = (int*)ws;
    for (int i = t; i < ZERO_WORDS; i += 512) wsi[i] = 0;
    if (t < NCLS) { sh_cnt[t] = 0; cur[t] = 0; }
    __syncthreads();
    const int c = labels[t];
    atomicAdd(&sh_cnt[c], 1);
    __syncthreads();
    if (t == 0) {
        int o = 0;
        for (int i = 0; i < NCLS; ++i) { sh_off[i] = o; ws->cls_off[i] = o; o += sh_cnt[i]; }
        ws->cls_off[NCLS] = o;
    }
    __syncthreads();
    const int slot = atomicAdd(&cur[c], 1);
    ws->cls_col[sh_off[c] + slot] = t;
}

// ---------------------------------------------------------------- poshist + direct (one dispatch)
__global__ __launch_bounds__(256) void phdir_kernel(const float* __restrict__ ip,
                                                    const float* __restrict__ logits,
                                                    const int* __restrict__ labels,
                                                    Accum* __restrict__ ws) {
    const int tid = threadIdx.x;
    if (blockIdx.x < PH_BLK) {
        // ---- pos (Sfr, Cnt) histogram: 8 threads per target row, 32 rows/block
        __shared__ float hfr[76][8];
        __shared__ float hcnt[76][8];
        __shared__ int   colL[SUPPORT];
        __shared__ int   offL[NCLS + 1];
        for (int i = tid; i < 76 * 8; i += 256) {
            (&hfr[0][0])[i] = 0.0f;
            (&hcnt[0][0])[i] = 0.0f;
        }
        for (int i = tid; i < SUPPORT; i += 256) colL[i] = ws->cls_col[i];
        if (tid <= NCLS) offL[tid] = ws->cls_off[tid];
        __syncthreads();

        const int row = (blockIdx.x * 256 + tid) >> 3;
        const int sl  = tid & 7;
        {
            const int c    = labels[SUPPORT + row];
            const int base = offL[c];
            const int cnt  = offL[c + 1] - base;
            const float* rptr = ip + (size_t)row * SUPPORT;
            for (int j = sl; j < cnt; j += 8) {
                const float s  = rptr[colL[base + j]];
                const float u  = s * 75.0f;
                const float fl = floorf(u);
                const int idx  = (int)fl;            // 0..74 guaranteed (s in [0,1))
                lds_fadd(&hfr[idx][sl],  u - fl);
                lds_fadd(&hcnt[idx][sl], 1.0f);
            }
        }
        __syncthreads();
        if (tid < 76) {
            float a = 0.0f, b = 0.0f;
            #pragma unroll
            for (int r = 0; r < 8; ++r) { a += hfr[tid][r]; b += hcnt[tid][r]; }
            if (a != 0.0f) unsafeAtomicAdd(&ws->hist_fr_sp[blockIdx.x & 7][tid], a);
            if (b != 0.0f) unsafeAtomicAdd(&ws->hist_cnt_sp[blockIdx.x & 7][tid], b);
        }
    } else {
        // ---- direct loss: 4 rows per wave, 16-lane group per row
        __shared__ float red[4];
        const int bid  = blockIdx.x - PH_BLK;
        const int wid  = tid >> 6;
        const int lane = tid & 63;
        const int sub  = lane >> 4;
        const int grpb = lane & ~15;

        float lsum = 0.0f;
        for (int q = bid * 4 + wid; q < NQUAD; q += DR_BLK * 4) {
            const float4 x = reinterpret_cast<const float4*>(logits)[q * 64 + lane];
            const int lab  = labels[SUPPORT + q * 4 + sub];
            float m = fmaxf(fmaxf(x.x, x.y), fmaxf(x.z, x.w));
            #pragma unroll
            for (int off = 1; off < 16; off <<= 1) m = fmaxf(m, __shfl_xor(m, off));
            float e = __expf(x.x - m) + __expf(x.y - m) + __expf(x.z - m) + __expf(x.w - m);
            #pragma unroll
            for (int off = 1; off < 16; off <<= 1) e += __shfl_xor(e, off);
            const int l3 = lab & 3;
            const float sel = l3 == 0 ? x.x : l3 == 1 ? x.y : l3 == 2 ? x.z : x.w;
            const float xl = __shfl(sel, grpb + (lab >> 2));
            if ((lane & 15) == 0) lsum += m + __logf(e) - xl;
        }
        #pragma unroll
        for (int off = 1; off < 64; off <<= 1) lsum += __shfl_xor(lsum, off);
        if (lane == 0) red[wid] = lsum;
        __syncthreads();
        if (tid == 0)
            unsafeAtomicAdd(&ws->nll_sum[bid & 7], red[0] + red[1] + red[2] + red[3]);
    }
}

// ---------------------------------------------------------------- stream (cdf prologue folded in)
// Prologue: reduce spread hists, one-lane scan -> fused Ta/Tb table in LDS
// (block 0 also stores spos/pos_num). Main: 64 contiguous rows, named-register
// 8-deep pipeline; per element: u=s*75; idx=(int)u; b64 read; add + fma.
__global__ __launch_bounds__(256, 4) void stream_kernel(const float* __restrict__ ip,
                                                        Accum* __restrict__ ws) {
    __shared__ float2 tab[76 * 16];   // 16-way replicated fused table
    __shared__ float Sfr[80], Cnt[80];
    __shared__ float Atab[80], Btab[80];
    __shared__ float red[4];
    const int tid = threadIdx.x;

    if (tid < 76) {
        float a = 0.0f, b = 0.0f;
        #pragma unroll
        for (int r = 0; r < 8; ++r) { a += ws->hist_fr_sp[r][tid]; b += ws->hist_cnt_sp[r][tid]; }
        Sfr[tid] = a; Cnt[tid] = b;
    }
    if (tid >= 76 && tid < 80) { Sfr[tid] = 0.0f; Cnt[tid] = 0.0f; }
    __syncthreads();
    if (tid == 0) {
        float prevS = 0.0f, prevN = 0.0f, cacc = 0.0f;
        double sp = 0.0, pn = 0.0;
        for (int i = 0; i <= 76; ++i) {
            const float Si = (i < 76) ? Sfr[i] : 0.0f;
            const float Ni = (i < 76) ? Cnt[i] : 0.0f;
            const float Hi = Si + prevN - prevS;     // pos soft-hist H[i]
            cacc += Hi;                              // C[i]
            if (i >= 1) {
                const int k = i - 1;
                Atab[k] = cacc + (float)k * Hi;      // C[k+1] + k*H[k+1]
                Btab[k] = Hi;                        // H[k+1]
                sp += (double)prevN * cacc - (double)prevS * Hi;
            }
            pn += (double)Ni;
            prevS = Si; prevN = Ni;
        }
        if (blockIdx.x == 0) { ws->spos = (float)sp; ws->pos_num = (float)pn; }
    }
    __syncthreads();
    const int c16 = tid & 15;
    for (int i = tid; i < 76 * 16; i += 256)
        tab[i] = make_float2(Atab[i >> 4], Btab[i >> 4]);
    __syncthreads();

    const float4* base = reinterpret_cast<const float4*>(ip)
                       + (size_t)blockIdx.x * (GS_ROWS * 128) + tid;

    float sa0 = 0.0f, sb0 = 0.0f, sa1 = 0.0f, sb1 = 0.0f;
    float4 qa0, qa1, qa2, qa3, qa4, qa5, qa6, qa7;
    float4 qb0, qb1, qb2, qb3, qb4, qb5, qb6, qb7;

#define LDA(T) { qa0 = base[((T)+0)*256]; qa1 = base[((T)+1)*256]; \
                 qa2 = base[((T)+2)*256]; qa3 = base[((T)+3)*256]; \
                 qa4 = base[((T)+4)*256]; qa5 = base[((T)+5)*256]; \
                 qa6 = base[((T)+6)*256]; qa7 = base[((T)+7)*256]; }
#define LDB(T) { qb0 = base[((T)+0)*256]; qb1 = base[((T)+1)*256]; \
                 qb2 = base[((T)+2)*256]; qb3 = base[((T)+3)*256]; \
                 qb4 = base[((T)+4)*256]; qb5 = base[((T)+5)*256]; \
                 qb6 = base[((T)+6)*256]; qb7 = base[((T)+7)*256]; }
#define PE(S, SA, SB) { const float u = (S) * 75.0f; const int idx = (int)u;   \
                        const float2 ab = tab[(idx << 4) + c16];               \
                        SA += ab.x; SB = fmaf(u, ab.y, SB); }
#define P1(Q) { PE(Q.x, sa0, sb0) PE(Q.y, sa1, sb1) PE(Q.z, sa0, sb0) PE(Q.w, sa1, sb1) }
#define PA()  { P1(qa0) P1(qa1) P1(qa2) P1(qa3) P1(qa4) P1(qa5) P1(qa6) P1(qa7) }
#define PB()  { P1(qb0) P1(qb1) P1(qb2) P1(qb3) P1(qb4) P1(qb5) P1(qb6) P1(qb7) }

    LDA(0);
    LDB(8);
    PA();  LDA(16);
    PB();  LDB(24);
    PA();
    PB();

#undef LDA
#undef LDB
#undef PE
#undef P1
#undef PA
#undef PB

    float s_all = (sa0 + sa1) - (sb0 + sb1);
    #pragma unroll
    for (int off = 1; off < 64; off <<= 1) s_all += __shfl_xor(s_all, off);
    if ((tid & 63) == 0) red[tid >> 6] = s_all;
    __syncthreads();
    if (tid == 0)
        unsafeAtomicAdd(&ws->sum_all[blockIdx.x & 7], red[0] + red[1] + red[2] + red[3]);
}

// ---------------------------------------------------------------- finalize
__global__ void final_kernel(const Accum* __restrict__ ws, float* __restrict__ out) {
    if (threadIdx.x == 0 && blockIdx.x == 0) {
        double S = 0.0, nll = 0.0;
        for (int i = 0; i < 8; ++i) {
            S   += (double)ws->sum_all[i];
            nll += (double)ws->nll_sum[i];
        }
        const double pos = (double)ws->pos_num;
        const double tot = (double)TARGET * (double)SUPPORT;
        out[0] = (float)((S - (double)ws->spos) / (pos * (tot - pos)));
        out[1] = (float)(nll / (double)TARGET);
    }
}

// ---------------------------------------------------------------- launch
extern "C" void kernel_launch(void* const* d_in, const int* in_sizes, int n_in,
                              void* d_out, int out_size, void* d_ws, size_t ws_size,
                              hipStream_t stream) {
    const float* logits = (const float*)d_in[0];   // (65024, 64) f32
    const float* ip     = (const float*)d_in[1];   // (65024, 512) f32
    const int*   labels = (const int*)d_in[2];     // (65536,) int
    float* out = (float*)d_out;
    Accum* ws  = (Accum*)d_ws;

    prep_kernel<<<1, 512, 0, stream>>>(labels, ws);
    phdir_kernel<<<PH_BLK + DR_BLK, 256, 0, stream>>>(ip, logits, labels, ws);
    stream_kernel<<<GS_BLK, 256, 0, stream>>>(ip, ws);
    final_kernel<<<1, 64, 0, stream>>>(ws, out);
}